// Round 9
// baseline (1298.259 us; speedup 1.0000x reference)
//
#include <hip/hip_runtime.h>
#include <stdint.h>

// ============================================================================
// S2S2S LSTM forecaster, MI355X.  Round 9: hidden-split across CU pairs.
//   rec_kernel: 32 blocks x 512 thr (1 block/CU, 32 CUs). Pair p = (blk&15),
//   sub s = blk>>4 computes hidden cols [128s,128s+128) for batch-tile p:
//   half the MFMAs (64/SIMD/step) and half the activations vs round 8.
//   Per-step h-exchange (4KB) + head partials via AGENT-scope relaxed atomics
//   (coherent point; per-XCD L2s are not cross-coherent). Flag protocol:
//   monotonic t0+t+1 per (phase,pair,sub), zeroed each call by init_kernel;
//   all 32 blocks co-resident -> no deadlock. Counted vmcnt(4) drains exports
//   while keeping the 4 xp prefetch loads in flight.
//   Inner math identical to round 8 (prescaled Whh + xp srcC, merged rcp).
// Output: cols 0..75 = future-decoder head, 76..90 = 0 (ref overwrites out_f).
// ============================================================================

typedef __attribute__((ext_vector_type(8))) short short8;  // 8 x bf16
typedef __attribute__((ext_vector_type(4))) float f32x4;   // MFMA acc
typedef __attribute__((ext_vector_type(2))) unsigned int u32x2;

#define L2E 1.4426950408889634f

__device__ __forceinline__ uint16_t f2bf(float f) {  // fp32 -> bf16 bits, RNE
  uint32_t x = __float_as_uint(f);
  x += 0x7fffu + ((x >> 16) & 1u);
  return (uint16_t)(x >> 16);
}
__device__ __forceinline__ uint32_t pk2(float a, float b) {
  return (uint32_t)f2bf(a) | ((uint32_t)f2bf(b) << 16);
}
__device__ __forceinline__ uint32_t cvtpk(float lo, float hi) {  // 1-inst pack
  uint32_t r;
  asm("v_cvt_pk_bf16_f32 %0, %1, %2" : "=v"(r) : "v"(lo), "v"(hi));
  return r;
}
__device__ __forceinline__ float bfhalf(uint32_t w, int hi) {  // bf16 -> fp32
  return __uint_as_float(hi ? (w & 0xffff0000u) : (w << 16));
}
__device__ __forceinline__ f32x4 MFMA(short8 a, short8 b, f32x4 c) {
  return __builtin_amdgcn_mfma_f32_16x16x32_bf16(a, b, c, 0, 0, 0);
}
__device__ __forceinline__ float ex2(float x) { return __builtin_amdgcn_exp2f(x); }
__device__ __forceinline__ float rcp(float x) { return __builtin_amdgcn_rcpf(x); }

__device__ __forceinline__ void lgkm_barrier() {
  __builtin_amdgcn_sched_barrier(0);
  asm volatile("s_waitcnt lgkmcnt(0)" ::: "memory");
  __builtin_amdgcn_s_barrier();
  __builtin_amdgcn_sched_barrier(0);
}
// drain oldest vmem ops (exports) but keep 4 xp prefetch loads in flight
__device__ __forceinline__ void vm_drain4() {
  __builtin_amdgcn_sched_barrier(0);
  asm volatile("s_waitcnt vmcnt(4)" ::: "memory");
  __builtin_amdgcn_sched_barrier(0);
}

// ---------------------------------------------------------------------------
__global__ void init_kernel(float* c_state, uint16_t* h_state, float* out,
                            uint32_t* flags) {
  int i = blockIdx.x * 256 + threadIdx.x;
  if (i < 65536) { c_state[i] = 0.f; h_state[i] = 0; }
  if (i < 256 * 91) out[i] = 0.f;
  if (i < 96) flags[i] = 0;   // 3 phases x 16 pairs x 2 subs
}

// ---------------------------------------------------------------------------
// xproj (unchanged from round 8): transposed, pre-scaled C^T fragments,
// xp[tc][btile][rowtile][lane][2], value = (x@Wih^T+b)*(g? +2log2e : -log2e).
// ---------------------------------------------------------------------------
template <int DIN>
__global__ __launch_bounds__(512) void xproj_kernel(
    const float* __restrict__ x, const float* __restrict__ Wih,
    const float* __restrict__ bias, uint32_t* __restrict__ xp,
    int t0, int T) {
  const int tid = threadIdx.x, w = tid >> 6, l = tid & 63;
  const int l16 = l & 15, lg = l >> 4;
  const int tc = blockIdx.x >> 1;
  const int sub = blockIdx.x & 1;
  const int t = t0 + tc;
  constexpr int KT = (DIN + 31) / 32;

  short8 bfr[8][KT];
  float4 bias4[8];
#pragma unroll
  for (int ni = 0; ni < 8; ++ni) {
    const int n = (w * 8 + ni) * 16 + l16;
    bias4[ni] = *(const float4*)&bias[(w * 8 + ni) * 16 + lg * 4];
#pragma unroll
    for (int kt = 0; kt < KT; ++kt) {
      const int k0 = kt * 32 + lg * 8;
      short8 fr;
#pragma unroll
      for (int e = 0; e < 8; ++e) fr[e] = 0;
      if (k0 + 8 <= DIN) {
        const float* s = Wih + (size_t)n * DIN + k0;
#pragma unroll
        for (int e = 0; e < 8; ++e) fr[e] = (short)f2bf(s[e]);
      }
      bfr[ni][kt] = fr;
    }
  }

  for (int mi = 0; mi < 8; ++mi) {
    const int btile = sub * 8 + mi;
    const int b = btile * 16 + l16;
    short8 af[KT];
#pragma unroll
    for (int kt = 0; kt < KT; ++kt) {
      const int k0 = kt * 32 + lg * 8;
      short8 fr;
#pragma unroll
      for (int e = 0; e < 8; ++e) fr[e] = 0;
      if (k0 + 8 <= DIN) {
        const float* s = x + ((size_t)b * T + t) * DIN + k0;
#pragma unroll
        for (int e = 0; e < 8; ++e) fr[e] = (short)f2bf(s[e]);
      }
      af[kt] = fr;
    }
#pragma unroll
    for (int ni = 0; ni < 8; ++ni) {
      f32x4 acc = {0.f, 0.f, 0.f, 0.f};
#pragma unroll
      for (int kt = 0; kt < KT; ++kt) acc = MFMA(bfr[ni][kt], af[kt], acc);
      const int nt = w * 8 + ni;
      const float sc = ((nt >> 4) == 2) ? (2.f * L2E) : -L2E;
      size_t idx = ((((size_t)tc * 16 + btile) * 64 + nt) * 64 + l) * 2;
      u32x2 v;
      v[0] = pk2((acc[0] + bias4[ni].x) * sc, (acc[1] + bias4[ni].y) * sc);
      v[1] = pk2((acc[2] + bias4[ni].z) * sc, (acc[3] + bias4[ni].w) * sc);
      *(u32x2*)(xp + idx) = v;
    }
  }
}

// ---------------------------------------------------------------------------
// Recurrent kernel, hidden-split. Wave w of sub s owns col-tile ctile=8s+w
// (16 hidden cols); gate-row tile (g) = g*16 + ctile. lane = (col
// ctile*16+lg*4+j, batch l16). Whh prescaled; kt<=5 -> bv[g*6+kt] (96 regs),
// kt6,7 -> B_lds. Per step: compute own 128 cols, export 8B/thread to hx
// (AGENT atomics), flag, spin partner, import partner half, barrier.
// ---------------------------------------------------------------------------
template <int DO_HEAD>
__global__ __launch_bounds__(512, 2) void rec_kernel(
    const uint32_t* __restrict__ xp, const float* __restrict__ Whh,
    float* __restrict__ c_state, uint16_t* __restrict__ h_state,
    float* __restrict__ out, const float* __restrict__ headW,
    const float* __restrict__ headb, uint32_t* __restrict__ flags,
    unsigned long long* __restrict__ hx, uint32_t* __restrict__ hxh,
    int ct, int t0, int phase) {
  __shared__ short8 B_lds[64 * 64];       // 65536 B (8 waves x 8 frags)
  __shared__ uint16_t h_lds[2][16][264];  // 16896 B (dbuf, pad 264)
  __shared__ float headbuf[16][8];        // 512 B    (total 82944 B)

  const int tid = threadIdx.x, w = tid >> 6, l = tid & 63;
  const int l16 = l & 15, lg = l >> 4;
  const int blk = blockIdx.x;
  const int pair = blk & 15, s = blk >> 4, sp = 1 - s;
  const int b0 = pair * 16;
  const int ctile = s * 8 + w;
  uint32_t* const pflag = flags + (phase * 16 + pair) * 2 + sp;
  uint32_t* const myflag = flags + (phase * 16 + pair) * 2 + s;

  // ---- Whh -> prescaled bf16 fragments: regs (kt0..5) / LDS (kt6,7) ----
  short8 bv[24];
#pragma unroll
  for (int g = 0; g < 4; ++g) {
    const float wsc = (g == 2) ? (2.f * L2E) : -L2E;  // gate order i,f,g,o
#pragma unroll
    for (int kt = 0; kt < 8; ++kt) {
      const int row = (g * 16 + ctile) * 16 + l16;
      const float* sw = Whh + (size_t)row * 256 + kt * 32 + lg * 8;
      short8 fr;
#pragma unroll
      for (int e = 0; e < 8; ++e) fr[e] = (short)f2bf(sw[e] * wsc);
      if (kt <= 5) bv[g * 6 + kt] = fr;
      else B_lds[(w * 8 + g * 2 + (kt - 6)) * 64 + l] = fr;
    }
  }

  // ---- state load ----
  float c_reg[4];
  {
    float4 c4 = *(const float4*)&c_state[(size_t)(b0 + l16) * 256 +
                                         ctile * 16 + lg * 4];
    c_reg[0] = c4.x; c_reg[1] = c4.y; c_reg[2] = c4.z; c_reg[3] = c4.w;
  }
  for (int idx = tid; idx < 16 * 256; idx += 512)
    h_lds[0][idx >> 8][idx & 255] = h_state[(size_t)(b0 + (idx >> 8)) * 256 + (idx & 255)];
  float4 hw4 = *(const float4*)&headW[ctile * 16 + lg * 4];
  const float hb = headb[0];

  // ---- xp prefetch for t=0 ----
  const uint32_t* xpb = xp + ((size_t)(pair * 64 + ctile) * 64 + l) * 2;
  u32x2 xpf[4];
#pragma unroll
  for (int g = 0; g < 4; ++g)
    xpf[g] = *(const u32x2*)(xpb + (size_t)g * 2048);

  __syncthreads();

  for (int t = 0; t < ct; ++t) {
    const int cur = t & 1, nxt = cur ^ 1;
    const int tn = (t + 1 < ct) ? t + 1 : t;
    const int par = t & 1;
    const uint32_t tgt = (uint32_t)(t0 + t + 1);
    float hsum = 0.f;

    // ---- MFMA: acc init from prescaled xp, 8-kt chain over full h ----
    f32x4 acc[4];
#pragma unroll
    for (int g = 0; g < 4; ++g) {
      f32x4 ai;
      ai[0] = bfhalf(xpf[g][0], 0);
      ai[1] = bfhalf(xpf[g][0], 1);
      ai[2] = bfhalf(xpf[g][1], 0);
      ai[3] = bfhalf(xpf[g][1], 1);
      acc[g] = ai;
    }
#pragma unroll
    for (int kt = 0; kt < 8; ++kt) {
      short8 hf = *(const short8*)(&h_lds[cur][l16][kt * 32 + lg * 8]);
#pragma unroll
      for (int g = 0; g < 4; ++g) {
        if (kt <= 5) acc[g] = MFMA(bv[g * 6 + kt], hf, acc[g]);
        else acc[g] = MFMA(B_lds[(w * 8 + g * 2 + (kt - 6)) * 64 + l], hf, acc[g]);
      }
    }

    // ---- activations (i,f,g,o), round-8 math ----
    float hv[4];
#pragma unroll
    for (int j = 0; j < 4; ++j) {
      float ei = ex2(acc[0][j]);
      float ef = ex2(acc[1][j]);
      float eg = ex2(acc[2][j]);
      float eo = ex2(acc[3][j]);
      float eip = 1.f + ei, egp = eg + 1.f, efp = 1.f + ef;
      float d1 = eip * egp;
      float R = rcp(d1 * efp);
      float sitg = (eg - 1.f) * efp * R;
      float cc = fmaf(c_reg[j] * d1, R, sitg);
      c_reg[j] = cc;
      float ec = ex2(cc * (2.f * L2E));
      float hh = (ec - 1.f) * rcp((1.f + eo) * (ec + 1.f));
      hv[j] = hh;
    }

    // ---- own h: local LDS write + export (AGENT atomic 8B) ----
    u32x2 hwrd;
    hwrd[0] = cvtpk(hv[0], hv[1]);
    hwrd[1] = cvtpk(hv[2], hv[3]);
    *(u32x2*)(&h_lds[nxt][l16][ctile * 16 + lg * 4]) = hwrd;
    {
      unsigned long long v64 =
          ((unsigned long long)hwrd[1] << 32) | (unsigned long long)hwrd[0];
      unsigned long long* dst =
          hx + ((size_t)((pair * 2 + s) * 2 + par) * 512) + (w * 4 + lg) * 16 + l16;
      __hip_atomic_store(dst, v64, __ATOMIC_RELAXED, __HIP_MEMORY_SCOPE_AGENT);
    }

    // ---- xp prefetch for t+1 (stays in flight across the exchange) ----
#pragma unroll
    for (int g = 0; g < 4; ++g)
      xpf[g] = *(const u32x2*)(xpb + (size_t)tn * 131072 + g * 2048);

    if (DO_HEAD) {
      float hp = fmaf(hv[0], hw4.x, fmaf(hv[1], hw4.y,
                 fmaf(hv[2], hw4.z, hv[3] * hw4.w)));
      hp += __shfl_xor(hp, 16);
      hp += __shfl_xor(hp, 32);
      if (lg == 0) headbuf[l16][w] = hp;
    }

    vm_drain4();     // drain own h export; 4 xp loads remain in flight
    lgkm_barrier();  // own h_lds[nxt] + headbuf visible; cur reads retired

    if (DO_HEAD) {
      if (tid < 16) {
        const float* hbp = headbuf[tid];
        hsum = hbp[0] + hbp[1] + hbp[2] + hbp[3] +
               hbp[4] + hbp[5] + hbp[6] + hbp[7];
        __hip_atomic_store(hxh + ((pair * 2 + s) * 2 + par) * 16 + tid,
                           __float_as_uint(hsum), __ATOMIC_RELAXED,
                           __HIP_MEMORY_SCOPE_AGENT);
      }
      vm_drain4();   // drain head export (wave 0); others no-op
    }
    if (tid == 0)
      __hip_atomic_store(myflag, tgt, __ATOMIC_RELAXED, __HIP_MEMORY_SCOPE_AGENT);

    // ---- spin for partner's step-t publication ----
    __builtin_amdgcn_sched_barrier(0);
    uint32_t f;
    do {
      f = __hip_atomic_load(pflag, __ATOMIC_RELAXED, __HIP_MEMORY_SCOPE_AGENT);
    } while ((int)(f - tgt) < 0);
    __builtin_amdgcn_sched_barrier(0);

    // ---- import partner half into h_lds[nxt] ----
    {
      const unsigned long long* src =
          hx + ((size_t)((pair * 2 + sp) * 2 + par) * 512) + (w * 4 + lg) * 16 + l16;
      unsigned long long pv =
          __hip_atomic_load(src, __ATOMIC_RELAXED, __HIP_MEMORY_SCOPE_AGENT);
      u32x2 pw;
      pw[0] = (uint32_t)pv;
      pw[1] = (uint32_t)(pv >> 32);
      *(u32x2*)(&h_lds[nxt][l16][sp * 128 + w * 16 + lg * 4]) = pw;
    }
    if (DO_HEAD && s == 0) {
      if (tid < 16) {
        uint32_t pp = __hip_atomic_load(
            hxh + ((pair * 2 + sp) * 2 + par) * 16 + tid,
            __ATOMIC_RELAXED, __HIP_MEMORY_SCOPE_AGENT);
        out[(size_t)(b0 + tid) * 91 + (t0 + t)] = hsum + __uint_as_float(pp) + hb;
      }
    }

    lgkm_barrier();  // partner h_lds writes visible
  }

  // ---- state writeback ----
  {
    float4 c4 = {c_reg[0], c_reg[1], c_reg[2], c_reg[3]};
    *(float4*)&c_state[(size_t)(b0 + l16) * 256 + ctile * 16 + lg * 4] = c4;
  }
  if (s == 0)
    for (int idx = tid; idx < 16 * 256; idx += 512)
      h_state[(size_t)(b0 + (idx >> 8)) * 256 + (idx & 255)] =
          h_lds[ct & 1][idx >> 8][idx & 255];
}

// ---------------------------------------------------------------------------
extern "C" void kernel_launch(void* const* d_in, const int* in_sizes, int n_in,
                              void* d_out, int out_size, void* d_ws, size_t ws_size,
                              hipStream_t stream) {
  const float* headW = (const float*)d_in[12];
  const float* headb = (const float*)d_in[13];
  float* out = (float*)d_out;

  char* ws = (char*)d_ws;
  float* c_state = (float*)ws;                           // 256 KB @ 0
  uint16_t* h_state = (uint16_t*)(ws + 262144);          // 128 KB
  uint32_t* flags = (uint32_t*)(ws + 393216);            // 384 B (4 KB slot)
  unsigned long long* hx = (unsigned long long*)(ws + 397312);  // 256 KB
  uint32_t* hxh = (uint32_t*)(ws + 659456);              // 4 KB
  uint32_t* xp = (uint32_t*)(ws + 667648);               // 512 KB per t

  int ct_max = 1;
  if (ws_size > 667648 + 512 * 1024) {
    size_t c = (ws_size - 667648) / (512 * 1024);
    ct_max = (c > 365) ? 365 : (int)c;
  }

  init_kernel<<<256, 256, 0, stream>>>(c_state, h_state, out, flags);

  struct Phase { const float* x; const float* Wih; const float* Whh; const float* b; int T; int D; int head; };
  Phase ph[3] = {
      {(const float*)d_in[0], (const float*)d_in[3], (const float*)d_in[4], (const float*)d_in[5],
       in_sizes[0] / (256 * 64), 64, 0},
      {(const float*)d_in[1], (const float*)d_in[6], (const float*)d_in[7], (const float*)d_in[8],
       in_sizes[1] / (256 * 32), 32, 0},
      {(const float*)d_in[2], (const float*)d_in[9], (const float*)d_in[10], (const float*)d_in[11],
       in_sizes[2] / (256 * 16), 16, 1},
  };

  for (int pi = 0; pi < 3; ++pi) {
    const Phase& P = ph[pi];
    for (int t0 = 0; t0 < P.T; t0 += ct_max) {
      int ct = (P.T - t0 < ct_max) ? (P.T - t0) : ct_max;
      dim3 g(ct * 2);
      if (P.D == 64)
        xproj_kernel<64><<<g, 512, 0, stream>>>(P.x, P.Wih, P.b, xp, t0, P.T);
      else if (P.D == 32)
        xproj_kernel<32><<<g, 512, 0, stream>>>(P.x, P.Wih, P.b, xp, t0, P.T);
      else
        xproj_kernel<16><<<g, 512, 0, stream>>>(P.x, P.Wih, P.b, xp, t0, P.T);
      if (P.head)
        rec_kernel<1><<<32, 512, 0, stream>>>(xp, P.Whh, c_state, h_state, out,
                                              headW, headb, flags, hx, hxh,
                                              ct, t0, pi);
      else
        rec_kernel<0><<<32, 512, 0, stream>>>(xp, P.Whh, c_state, h_state, out,
                                              headW, headb, flags, hx, hxh,
                                              ct, t0, pi);
    }
  }
}

// Round 10
// 1248.268 us; speedup vs baseline: 1.0400x; 1.0400x over previous
//
#include <hip/hip_runtime.h>
#include <stdint.h>

// ============================================================================
// S2S2S LSTM forecaster, MI355X.  Round 10: hidden-split with DEFERRED
// exchange (critical-path fix of round 9).
//   32 blocks x 512 thr; pair p=blk&15, sub s=blk>>4 owns hidden cols
//   [128s,128s+128). Per step: spin partner flag (published one iteration
//   ago -> ~1 poll), issue import, run OWN-half kts (hides import), barrier,
//   PARTNER-half kts, activations, export+flag. Head partials combine with
//   one-step deferral under the same flag. Final h-writeback from registers
//   + final import (s==0). Whh frags stored own-relative: own kts bv[g*6+0..3],
//   partner kts bv[g*6+4..5] + B_lds (compile-time reg indices; runtime s
//   only in addresses). Inner math identical to rounds 8/9.
// Output: cols 0..75 = future-decoder head, 76..90 = 0 (ref overwrites out_f).
// ============================================================================

typedef __attribute__((ext_vector_type(8))) short short8;  // 8 x bf16
typedef __attribute__((ext_vector_type(4))) float f32x4;   // MFMA acc
typedef __attribute__((ext_vector_type(2))) unsigned int u32x2;

#define L2E 1.4426950408889634f

__device__ __forceinline__ uint16_t f2bf(float f) {  // fp32 -> bf16 bits, RNE
  uint32_t x = __float_as_uint(f);
  x += 0x7fffu + ((x >> 16) & 1u);
  return (uint16_t)(x >> 16);
}
__device__ __forceinline__ uint32_t pk2(float a, float b) {
  return (uint32_t)f2bf(a) | ((uint32_t)f2bf(b) << 16);
}
__device__ __forceinline__ uint32_t cvtpk(float lo, float hi) {  // 1-inst pack
  uint32_t r;
  asm("v_cvt_pk_bf16_f32 %0, %1, %2" : "=v"(r) : "v"(lo), "v"(hi));
  return r;
}
__device__ __forceinline__ float bfhalf(uint32_t w, int hi) {  // bf16 -> fp32
  return __uint_as_float(hi ? (w & 0xffff0000u) : (w << 16));
}
__device__ __forceinline__ f32x4 MFMA(short8 a, short8 b, f32x4 c) {
  return __builtin_amdgcn_mfma_f32_16x16x32_bf16(a, b, c, 0, 0, 0);
}
__device__ __forceinline__ float ex2(float x) { return __builtin_amdgcn_exp2f(x); }
__device__ __forceinline__ float rcp(float x) { return __builtin_amdgcn_rcpf(x); }

__device__ __forceinline__ void lgkm_barrier() {
  __builtin_amdgcn_sched_barrier(0);
  asm volatile("s_waitcnt lgkmcnt(0)" ::: "memory");
  __builtin_amdgcn_s_barrier();
  __builtin_amdgcn_sched_barrier(0);
}
// drain oldest vmem ops but keep 4 xp prefetch loads in flight
__device__ __forceinline__ void vm_drain4() {
  __builtin_amdgcn_sched_barrier(0);
  asm volatile("s_waitcnt vmcnt(4)" ::: "memory");
  __builtin_amdgcn_sched_barrier(0);
}

// ---------------------------------------------------------------------------
__global__ void init_kernel(float* c_state, uint16_t* h_state, float* out,
                            uint32_t* flags) {
  int i = blockIdx.x * 256 + threadIdx.x;
  if (i < 65536) { c_state[i] = 0.f; h_state[i] = 0; }
  if (i < 256 * 91) out[i] = 0.f;
  if (i < 96) flags[i] = 0;   // 3 phases x 16 pairs x 2 subs
}

// ---------------------------------------------------------------------------
// xproj (unchanged): transposed, pre-scaled C^T fragments,
// xp[tc][btile][rowtile][lane][2], value = (x@Wih^T+b)*(g? +2log2e : -log2e).
// ---------------------------------------------------------------------------
template <int DIN>
__global__ __launch_bounds__(512) void xproj_kernel(
    const float* __restrict__ x, const float* __restrict__ Wih,
    const float* __restrict__ bias, uint32_t* __restrict__ xp,
    int t0, int T) {
  const int tid = threadIdx.x, w = tid >> 6, l = tid & 63;
  const int l16 = l & 15, lg = l >> 4;
  const int tc = blockIdx.x >> 1;
  const int sub = blockIdx.x & 1;
  const int t = t0 + tc;
  constexpr int KT = (DIN + 31) / 32;

  short8 bfr[8][KT];
  float4 bias4[8];
#pragma unroll
  for (int ni = 0; ni < 8; ++ni) {
    const int n = (w * 8 + ni) * 16 + l16;
    bias4[ni] = *(const float4*)&bias[(w * 8 + ni) * 16 + lg * 4];
#pragma unroll
    for (int kt = 0; kt < KT; ++kt) {
      const int k0 = kt * 32 + lg * 8;
      short8 fr;
#pragma unroll
      for (int e = 0; e < 8; ++e) fr[e] = 0;
      if (k0 + 8 <= DIN) {
        const float* s = Wih + (size_t)n * DIN + k0;
#pragma unroll
        for (int e = 0; e < 8; ++e) fr[e] = (short)f2bf(s[e]);
      }
      bfr[ni][kt] = fr;
    }
  }

  for (int mi = 0; mi < 8; ++mi) {
    const int btile = sub * 8 + mi;
    const int b = btile * 16 + l16;
    short8 af[KT];
#pragma unroll
    for (int kt = 0; kt < KT; ++kt) {
      const int k0 = kt * 32 + lg * 8;
      short8 fr;
#pragma unroll
      for (int e = 0; e < 8; ++e) fr[e] = 0;
      if (k0 + 8 <= DIN) {
        const float* s = x + ((size_t)b * T + t) * DIN + k0;
#pragma unroll
        for (int e = 0; e < 8; ++e) fr[e] = (short)f2bf(s[e]);
      }
      af[kt] = fr;
    }
#pragma unroll
    for (int ni = 0; ni < 8; ++ni) {
      f32x4 acc = {0.f, 0.f, 0.f, 0.f};
#pragma unroll
      for (int kt = 0; kt < KT; ++kt) acc = MFMA(bfr[ni][kt], af[kt], acc);
      const int nt = w * 8 + ni;
      const float sc = ((nt >> 4) == 2) ? (2.f * L2E) : -L2E;
      size_t idx = ((((size_t)tc * 16 + btile) * 64 + nt) * 64 + l) * 2;
      u32x2 v;
      v[0] = pk2((acc[0] + bias4[ni].x) * sc, (acc[1] + bias4[ni].y) * sc);
      v[1] = pk2((acc[2] + bias4[ni].z) * sc, (acc[3] + bias4[ni].w) * sc);
      *(u32x2*)(xp + idx) = v;
    }
  }
}

// ---------------------------------------------------------------------------
// Recurrent kernel, hidden-split + deferred exchange.
// Wave w of sub s owns col-tile ctile=8s+w; gate-row tile g*16+ctile.
// Own kts = 4s..4s+3 (bv[g*6+0..3]); partner kts = 4sp..4sp+3
// (bv[g*6+4..5] for first two, B_lds for last two).
// ---------------------------------------------------------------------------
template <int DO_HEAD>
__global__ __launch_bounds__(512, 2) void rec_kernel(
    const uint32_t* __restrict__ xp, const float* __restrict__ Whh,
    float* __restrict__ c_state, uint16_t* __restrict__ h_state,
    float* __restrict__ out, const float* __restrict__ headW,
    const float* __restrict__ headb, uint32_t* __restrict__ flags,
    unsigned long long* __restrict__ hx, uint32_t* __restrict__ hxh,
    int ct, int t0, int phase) {
  __shared__ short8 B_lds[64 * 64];       // 65536 B
  __shared__ uint16_t h_lds[2][16][264];  // 16896 B (dbuf, pad 264)
  __shared__ float headbuf[16][8];        // 512 B

  const int tid = threadIdx.x, w = tid >> 6, l = tid & 63;
  const int l16 = l & 15, lg = l >> 4;
  const int blk = blockIdx.x;
  const int pair = blk & 15, s = blk >> 4, sp = 1 - s;
  const int b0 = pair * 16;
  const int ctile = s * 8 + w;
  uint32_t* const pflag = flags + (phase * 16 + pair) * 2 + sp;
  uint32_t* const myflag = flags + (phase * 16 + pair) * 2 + s;

  // ---- Whh -> prescaled bf16 fragments, own-relative storage ----
  // kk 0..3 -> own kt 4s+kk  -> bv[g*6+kk]
  // kk 4..5 -> partner kt 4sp+(kk-4) -> bv[g*6+kk]
  // kk 6..7 -> partner kt 4sp+(kk-4) -> B_lds[(w*8 + g*2 + (kk-6))*64 + l]
  short8 bv[24];
#pragma unroll
  for (int g = 0; g < 4; ++g) {
    const float wsc = (g == 2) ? (2.f * L2E) : -L2E;  // gate order i,f,g,o
#pragma unroll
    for (int kk = 0; kk < 8; ++kk) {
      const int kt = (kk < 4) ? (4 * s + kk) : (4 * sp + (kk - 4));
      const int row = (g * 16 + ctile) * 16 + l16;
      const float* sw = Whh + (size_t)row * 256 + kt * 32 + lg * 8;
      short8 fr;
#pragma unroll
      for (int e = 0; e < 8; ++e) fr[e] = (short)f2bf(sw[e] * wsc);
      if (kk <= 5) bv[g * 6 + kk] = fr;
      else B_lds[(w * 8 + g * 2 + (kk - 6)) * 64 + l] = fr;
    }
  }

  // ---- state load ----
  float c_reg[4];
  {
    float4 c4 = *(const float4*)&c_state[(size_t)(b0 + l16) * 256 +
                                         ctile * 16 + lg * 4];
    c_reg[0] = c4.x; c_reg[1] = c4.y; c_reg[2] = c4.z; c_reg[3] = c4.w;
  }
  for (int idx = tid; idx < 16 * 256; idx += 512)
    h_lds[0][idx >> 8][idx & 255] = h_state[(size_t)(b0 + (idx >> 8)) * 256 + (idx & 255)];
  float4 hw4 = *(const float4*)&headW[ctile * 16 + lg * 4];
  const float hb = headb[0];

  // ---- xp prefetch for t=0 ----
  const uint32_t* xpb = xp + ((size_t)(pair * 64 + ctile) * 64 + l) * 2;
  u32x2 xpf[4];
#pragma unroll
  for (int g = 0; g < 4; ++g)
    xpf[g] = *(const u32x2*)(xpb + (size_t)g * 2048);

  __syncthreads();

  u32x2 h_last;            // own bf16 h of the latest step (for writeback)
  h_last[0] = 0; h_last[1] = 0;
  float hsum_prev = 0.f;   // tid<16: own head partial of previous step

  for (int t = 0; t < ct; ++t) {
    const int cur = t & 1, nxt = cur ^ 1;
    const int tn = (t + 1 < ct) ? t + 1 : t;
    const int par = t & 1;

    // ---- (A) spin for partner's h(t)-input half; issue import early ----
    unsigned long long pv = 0ull;
    if (t > 0) {
      const uint32_t tgt = (uint32_t)(t0 + t);
      __builtin_amdgcn_sched_barrier(0);
      uint32_t f;
      do {
        f = __hip_atomic_load(pflag, __ATOMIC_RELAXED, __HIP_MEMORY_SCOPE_AGENT);
      } while ((int)(f - tgt) < 0);
      __builtin_amdgcn_sched_barrier(0);
      pv = __hip_atomic_load(
          hx + ((size_t)((pair * 2 + sp) * 2 + ((t - 1) & 1)) * 512) +
              (w * 4 + lg) * 16 + l16,
          __ATOMIC_RELAXED, __HIP_MEMORY_SCOPE_AGENT);
      // deferred head combine for step t-1 (covered by the same flag)
      if (DO_HEAD && s == 0 && tid < 16) {
        uint32_t pp = __hip_atomic_load(
            hxh + ((pair * 2 + sp) * 2 + ((t - 1) & 1)) * 16 + tid,
            __ATOMIC_RELAXED, __HIP_MEMORY_SCOPE_AGENT);
        out[(size_t)(b0 + tid) * 91 + (t0 + t - 1)] =
            hsum_prev + __uint_as_float(pp) + hb;
      }
    }

    // ---- (C) acc init from prescaled xp + OWN-half kts (hides import) ----
    f32x4 acc[4];
#pragma unroll
    for (int g = 0; g < 4; ++g) {
      f32x4 ai;
      ai[0] = bfhalf(xpf[g][0], 0);
      ai[1] = bfhalf(xpf[g][0], 1);
      ai[2] = bfhalf(xpf[g][1], 0);
      ai[3] = bfhalf(xpf[g][1], 1);
      acc[g] = ai;
    }
#pragma unroll
    for (int kk = 0; kk < 4; ++kk) {
      short8 hf = *(const short8*)(&h_lds[cur][l16][(4 * s + kk) * 32 + lg * 8]);
#pragma unroll
      for (int g = 0; g < 4; ++g)
        acc[g] = MFMA(bv[g * 6 + kk], hf, acc[g]);
    }

    // ---- (D) land partner half into h_lds[cur]; make visible ----
    if (t > 0) {
      u32x2 pw;
      pw[0] = (uint32_t)pv;
      pw[1] = (uint32_t)(pv >> 32);
      *(u32x2*)(&h_lds[cur][l16][sp * 128 + w * 16 + lg * 4]) = pw;
      lgkm_barrier();
    }

    // ---- (E) PARTNER-half kts ----
#pragma unroll
    for (int kk = 0; kk < 4; ++kk) {
      short8 hf = *(const short8*)(&h_lds[cur][l16][(4 * sp + kk) * 32 + lg * 8]);
#pragma unroll
      for (int g = 0; g < 4; ++g) {
        if (kk < 2) acc[g] = MFMA(bv[g * 6 + 4 + kk], hf, acc[g]);
        else acc[g] = MFMA(B_lds[(w * 8 + g * 2 + (kk - 2)) * 64 + l], hf, acc[g]);
      }
    }

    // ---- (F) activations (i,f,g,o) ----
    float hv[4];
#pragma unroll
    for (int j = 0; j < 4; ++j) {
      float ei = ex2(acc[0][j]);
      float ef = ex2(acc[1][j]);
      float eg = ex2(acc[2][j]);
      float eo = ex2(acc[3][j]);
      float eip = 1.f + ei, egp = eg + 1.f, efp = 1.f + ef;
      float d1 = eip * egp;
      float R = rcp(d1 * efp);
      float sitg = (eg - 1.f) * efp * R;
      float cc = fmaf(c_reg[j] * d1, R, sitg);
      c_reg[j] = cc;
      float ec = ex2(cc * (2.f * L2E));
      float hh = (ec - 1.f) * rcp((1.f + eo) * (ec + 1.f));
      hv[j] = hh;
    }

    // ---- (G) own h: local LDS write + export store ----
    h_last[0] = cvtpk(hv[0], hv[1]);
    h_last[1] = cvtpk(hv[2], hv[3]);
    *(u32x2*)(&h_lds[nxt][l16][ctile * 16 + lg * 4]) = h_last;
    {
      unsigned long long v64 =
          ((unsigned long long)h_last[1] << 32) | (unsigned long long)h_last[0];
      __hip_atomic_store(
          hx + ((size_t)((pair * 2 + s) * 2 + par) * 512) + (w * 4 + lg) * 16 + l16,
          v64, __ATOMIC_RELAXED, __HIP_MEMORY_SCOPE_AGENT);
    }

    // ---- (H) xp prefetch for t+1 (stays in flight) ----
#pragma unroll
    for (int g = 0; g < 4; ++g)
      xpf[g] = *(const u32x2*)(xpb + (size_t)tn * 131072 + g * 2048);

    // ---- (I) head partial reduce ----
    if (DO_HEAD) {
      float hp = fmaf(hv[0], hw4.x, fmaf(hv[1], hw4.y,
                 fmaf(hv[2], hw4.z, hv[3] * hw4.w)));
      hp += __shfl_xor(hp, 16);
      hp += __shfl_xor(hp, 32);
      if (lg == 0) headbuf[l16][w] = hp;
    }

    vm_drain4();     // own h export drained; 4 xp loads remain
    lgkm_barrier();  // barrier B: h_lds[nxt] own half + headbuf visible

    // ---- (K) own head partial publish; (L) flag ----
    if (DO_HEAD) {
      if (tid < 16) {
        const float* hbp = headbuf[tid];
        hsum_prev = hbp[0] + hbp[1] + hbp[2] + hbp[3] +
                    hbp[4] + hbp[5] + hbp[6] + hbp[7];
        __hip_atomic_store(hxh + ((pair * 2 + s) * 2 + par) * 16 + tid,
                           __float_as_uint(hsum_prev), __ATOMIC_RELAXED,
                           __HIP_MEMORY_SCOPE_AGENT);
      }
      vm_drain4();   // hxh drained (wave 0); others no-op
    }
    if (tid == 0)
      __hip_atomic_store(myflag, (uint32_t)(t0 + t + 1), __ATOMIC_RELAXED,
                         __HIP_MEMORY_SCOPE_AGENT);
  }

  // ---- c writeback (both subs, own cols) ----
  {
    float4 c4 = {c_reg[0], c_reg[1], c_reg[2], c_reg[3]};
    *(float4*)&c_state[(size_t)(b0 + l16) * 256 + ctile * 16 + lg * 4] = c4;
  }

  // ---- s==0: final import -> h_state (both halves) + final head col ----
  if (s == 0) {
    const uint32_t tgt = (uint32_t)(t0 + ct);
    __builtin_amdgcn_sched_barrier(0);
    uint32_t f;
    do {
      f = __hip_atomic_load(pflag, __ATOMIC_RELAXED, __HIP_MEMORY_SCOPE_AGENT);
    } while ((int)(f - tgt) < 0);
    __builtin_amdgcn_sched_barrier(0);
    unsigned long long pv = __hip_atomic_load(
        hx + ((size_t)((pair * 2 + sp) * 2 + ((ct - 1) & 1)) * 512) +
            (w * 4 + lg) * 16 + l16,
        __ATOMIC_RELAXED, __HIP_MEMORY_SCOPE_AGENT);
    u32x2 pw;
    pw[0] = (uint32_t)pv;
    pw[1] = (uint32_t)(pv >> 32);
    *(u32x2*)&h_state[(size_t)(b0 + l16) * 256 + 128 + w * 16 + lg * 4] = pw;
    *(u32x2*)&h_state[(size_t)(b0 + l16) * 256 + w * 16 + lg * 4] = h_last;
    if (DO_HEAD && tid < 16) {
      uint32_t pp = __hip_atomic_load(
          hxh + ((pair * 2 + sp) * 2 + ((ct - 1) & 1)) * 16 + tid,
          __ATOMIC_RELAXED, __HIP_MEMORY_SCOPE_AGENT);
      out[(size_t)(b0 + tid) * 91 + (t0 + ct - 1)] =
          hsum_prev + __uint_as_float(pp) + hb;
    }
  }
}

// ---------------------------------------------------------------------------
extern "C" void kernel_launch(void* const* d_in, const int* in_sizes, int n_in,
                              void* d_out, int out_size, void* d_ws, size_t ws_size,
                              hipStream_t stream) {
  const float* headW = (const float*)d_in[12];
  const float* headb = (const float*)d_in[13];
  float* out = (float*)d_out;

  char* ws = (char*)d_ws;
  float* c_state = (float*)ws;                           // 256 KB @ 0
  uint16_t* h_state = (uint16_t*)(ws + 262144);          // 128 KB
  uint32_t* flags = (uint32_t*)(ws + 393216);            // 384 B (4 KB slot)
  unsigned long long* hx = (unsigned long long*)(ws + 397312);  // 256 KB
  uint32_t* hxh = (uint32_t*)(ws + 659456);              // 4 KB
  uint32_t* xp = (uint32_t*)(ws + 667648);               // 512 KB per t

  int ct_max = 1;
  if (ws_size > 667648 + 512 * 1024) {
    size_t c = (ws_size - 667648) / (512 * 1024);
    ct_max = (c > 365) ? 365 : (int)c;
  }

  init_kernel<<<256, 256, 0, stream>>>(c_state, h_state, out, flags);

  struct Phase { const float* x; const float* Wih; const float* Whh; const float* b; int T; int D; int head; };
  Phase ph[3] = {
      {(const float*)d_in[0], (const float*)d_in[3], (const float*)d_in[4], (const float*)d_in[5],
       in_sizes[0] / (256 * 64), 64, 0},
      {(const float*)d_in[1], (const float*)d_in[6], (const float*)d_in[7], (const float*)d_in[8],
       in_sizes[1] / (256 * 32), 32, 0},
      {(const float*)d_in[2], (const float*)d_in[9], (const float*)d_in[10], (const float*)d_in[11],
       in_sizes[2] / (256 * 16), 16, 1},
  };

  for (int pi = 0; pi < 3; ++pi) {
    const Phase& P = ph[pi];
    for (int t0 = 0; t0 < P.T; t0 += ct_max) {
      int ct = (P.T - t0 < ct_max) ? (P.T - t0) : ct_max;
      dim3 g(ct * 2);
      if (P.D == 64)
        xproj_kernel<64><<<g, 512, 0, stream>>>(P.x, P.Wih, P.b, xp, t0, P.T);
      else if (P.D == 32)
        xproj_kernel<32><<<g, 512, 0, stream>>>(P.x, P.Wih, P.b, xp, t0, P.T);
      else
        xproj_kernel<16><<<g, 512, 0, stream>>>(P.x, P.Wih, P.b, xp, t0, P.T);
      if (P.head)
        rec_kernel<1><<<32, 512, 0, stream>>>(xp, P.Whh, c_state, h_state, out,
                                              headW, headb, flags, hx, hxh,
                                              ct, t0, pi);
      else
        rec_kernel<0><<<32, 512, 0, stream>>>(xp, P.Whh, c_state, h_state, out,
                                              headW, headb, flags, hx, hxh,
                                              ct, t0, pi);
    }
  }
}